// Round 10
// baseline (299.201 us; speedup 1.0000x reference)
//
#include <hip/hip_runtime.h>
#include <hip/hip_bf16.h>

#define NB   32
#define CH   64
#define LL   2048
#define OUTC 128

typedef float  f32x4  __attribute__((ext_vector_type(4)));
typedef short  s16x8  __attribute__((ext_vector_type(8)));
typedef short  s16x4  __attribute__((ext_vector_type(4)));
typedef unsigned short u16;

__device__ __forceinline__ u16 f2bf(float f) {
  unsigned int u = __builtin_bit_cast(unsigned int, f);
  u += 0x7FFFu + ((u >> 16) & 1u);           // RNE (scalar epilogue use)
  return (u16)(u >> 16);
}

// 8x fp32 -> 8x bf16 via v_cvt_pk_bf16_f32 (compiler-emitted, RNE)
__device__ __forceinline__ s16x8 pack8c(const float* v) {
  s16x8 r;
#pragma unroll
  for (int j = 0; j < 8; j += 2) {
    __hip_bfloat162 h = __float22bfloat162_rn(make_float2(v[j], v[j + 1]));
    short2 s;
    __builtin_memcpy(&s, &h, sizeof(s));
    r[j] = s.x; r[j + 1] = s.y;
  }
  return r;
}

__device__ __forceinline__ s16x4 pack4c(const f32x4& v) {
  s16x4 r;
  __hip_bfloat162 h0 = __float22bfloat162_rn(make_float2(v[0], v[1]));
  __hip_bfloat162 h1 = __float22bfloat162_rn(make_float2(v[2], v[3]));
  short2 s0, s1;
  __builtin_memcpy(&s0, &h0, sizeof(s0));
  __builtin_memcpy(&s1, &h1, sizeof(s1));
  r[0] = s0.x; r[1] = s0.y; r[2] = s1.x; r[3] = s1.y;
  return r;
}

// ---------------------------------------------------------------------------
// K0: x (fp32->bf16), W (fp32->bf16)
// ---------------------------------------------------------------------------
#define NX (NB * CH * LL)          // 4,194,304
#define NW (OUTC * 3 * CH)         // 24,576
__global__ __launch_bounds__(256)
void cvt_inputs(const float* __restrict__ x, const float* __restrict__ W,
                u16* __restrict__ xb, u16* __restrict__ Wb)
{
  const size_t t8 = ((size_t)blockIdx.x * 256 + threadIdx.x) * 8;
  if (t8 < NX) {
    float v[8];
    *(f32x4*)(v)     = *(const f32x4*)(x + t8);
    *(f32x4*)(v + 4) = *(const f32x4*)(x + t8 + 4);
    *(s16x8*)(xb + t8) = pack8c(v);
  } else if (t8 - NX < NW) {
    const size_t w8 = t8 - NX;
    float v[8];
    *(f32x4*)(v)     = *(const f32x4*)(W + w8);
    *(f32x4*)(v + 4) = *(const f32x4*)(W + w8 + 4);
    *(s16x8*)(Wb + w8) = pack8c(v);
  }
}

// ---------------------------------------------------------------------------
// K1: y1[n] = xb[n] * m[n]  (+ writes mP bf16 B-fragments for K2)
// 64-col tiles, 128-thread blocks (2 waves), grid 1024 -> 4 independent
// blocks/CU. Quad-buffered gload_lds, A-regs prefetched dist 1, counted
// vmcnt + raw s_barrier. Per-wave per-step issue [A:4][G:4][St:2] (same
// literals as the 256-thread variant).
// ---------------------------------------------------------------------------
__global__ __launch_bounds__(128)
void prop1_pack(const u16* __restrict__ xb, const float* __restrict__ m,
                u16* __restrict__ y1, u16* __restrict__ mP)
{
  __shared__ float smem[4][32 * 64];   // 32 KiB quad-buffered 32x64 fp32 tile

  const int n    = blockIdx.x >> 5;
  const int lt   = blockIdx.x & 31;
  const int tid  = threadIdx.x;
  const int wave = tid >> 6;
  const int lane = tid & 63;
  const int l15  = lane & 15;
  const int g4   = lane >> 4;
  const int colb = lt * 64 + wave * 32;

  const float* mn = m + (size_t)n * LL * LL + lt * 64;
  // chunk i: LDS dwords [(wave*4+i)*256, +256) = rows (wave*4+i)*4..+3;
  // lane l covers row +(l>>4), col (l&15)*4  (256B segments, coalesced)
  const float* gsrc = mn + (size_t)(wave * 16 + (lane >> 4)) * LL + (lane & 15) * 4;
  const u16*   ap   = xb + (size_t)n * CH * LL + (size_t)l15 * LL + g4 * 8;
  u16* q0 = mP + (((size_t)n * 64 * LL + colb + l15) * 4 + g4) * 8; // + kb*65536, h*512
  u16* o  = y1 + (size_t)n * CH * LL + colb + l15;

  f32x4 acc[4][2];
#pragma unroll
  for (int f = 0; f < 4; ++f)
#pragma unroll
    for (int h = 0; h < 2; ++h)
#pragma unroll
      for (int r = 0; r < 4; ++r) acc[f][h][r] = 0.f;

  s16x8 aP[4], aQ[4];

#define ALOAD(R, KB)                                                          \
  { const u16* _ap = ap + (KB) * 32;                                          \
    _Pragma("unroll") for (int f = 0; f < 4; ++f)                             \
      R[f] = *(const s16x8*)(_ap + (size_t)(f * 16) * LL); }

#define GLOAD(BI, KB)                                                         \
  { float* _sb = smem[BI];                                                    \
    _Pragma("unroll") for (int i = 0; i < 4; ++i) {                           \
      const float* _g = gsrc + (size_t)((KB) * 32 + i * 4) * LL;              \
      __builtin_amdgcn_global_load_lds(                                       \
        (const __attribute__((address_space(1))) void*)_g,                    \
        (__attribute__((address_space(3))) void*)(_sb + (wave * 4 + i) * 256),\
        16, 0, 0); } }

  // prologue: A(0) FIRST (oldest), then tiles 0,1,2
  ALOAD(aP, 0)
  __builtin_amdgcn_sched_barrier(0);
  GLOAD(0, 0) GLOAD(1, 1) GLOAD(2, 2)
  __builtin_amdgcn_sched_barrier(0);
  asm volatile("s_waitcnt vmcnt(8)" ::: "memory");   // tile 0 landed
  __builtin_amdgcn_s_barrier();
  __builtin_amdgcn_sched_barrier(0);

#define K1_STEP(KB, CUR, NXT, VN, LAST)                                       \
  {                                                                           \
    if (!(LAST)) {                                                            \
      ALOAD(NXT, ((KB) + 1 < 64 ? (KB) + 1 : 63))                             \
      __builtin_amdgcn_sched_barrier(0);                                      \
      GLOAD(((KB) + 3) & 3, ((KB) + 3 < 64 ? (KB) + 3 : 63))                  \
      __builtin_amdgcn_sched_barrier(0);                                      \
    }                                                                         \
    const float* _t = smem[(KB) & 3] + wave * 32 + l15;                       \
    float _bv0[8], _bv1[8];                                                   \
    _Pragma("unroll") for (int j = 0; j < 8; ++j) {                           \
      _bv0[j] = _t[(g4 * 8 + j) * 64];                                        \
      _bv1[j] = _t[(g4 * 8 + j) * 64 + 16];                                   \
    }                                                                         \
    s16x8 _b0 = pack8c(_bv0), _b1 = pack8c(_bv1);                             \
    u16* _q = q0 + (size_t)(KB) * 65536;                                      \
    *(s16x8*)(_q)       = _b0;                                                \
    *(s16x8*)(_q + 512) = _b1;                                                \
    _Pragma("unroll") for (int f = 0; f < 4; ++f) {                           \
      acc[f][0] = __builtin_amdgcn_mfma_f32_16x16x32_bf16(CUR[f], _b0, acc[f][0], 0, 0, 0); \
      acc[f][1] = __builtin_amdgcn_mfma_f32_16x16x32_bf16(CUR[f], _b1, acc[f][1], 0, 0, 0); \
    }                                                                         \
    if (!(LAST)) {                                                            \
      __builtin_amdgcn_sched_barrier(0);                                      \
      asm volatile("s_waitcnt vmcnt(" VN ")" ::: "memory");                   \
      __builtin_amdgcn_s_barrier();                                           \
      __builtin_amdgcn_sched_barrier(0);                                      \
    }                                                                         \
  }

  K1_STEP(0, aP, aQ, "14", false)   // retire G(1): G2+A1+G3+St0 = 14 newer
  K1_STEP(1, aQ, aP, "20", false)   // retire G(2): 20 newer
#pragma unroll 1
  for (int kb = 2; kb < 62; kb += 2) {
    K1_STEP(kb,     aP, aQ, "22", false)
    K1_STEP(kb + 1, aQ, aP, "22", false)
  }
  K1_STEP(62, aP, aQ, "22", false)
  K1_STEP(63, aQ, aP, "0",  true)

#pragma unroll
  for (int f = 0; f < 4; ++f)
#pragma unroll
    for (int r = 0; r < 4; ++r) {
      const int row = f * 16 + g4 * 4 + r;
      o[(size_t)row * LL]      = f2bf(acc[f][0][r]);
      o[(size_t)row * LL + 16] = f2bf(acc[f][1][r]);
    }
}

// ---------------------------------------------------------------------------
// K2: y2 = y1 * m (from mP, kb REVERSED so the L3-resident tail of mP written
// by K1 is consumed first) FUSED with projection: out = Wb*[xb;y1;y2] + b.
// 64-col tiles, 128-thread blocks, grid 1024.
// ---------------------------------------------------------------------------
__global__ __launch_bounds__(128)
void prop2_proj(const u16* __restrict__ y1, const u16* __restrict__ mP,
                const u16* __restrict__ xb, const u16* __restrict__ Wb,
                const float* __restrict__ bias, float* __restrict__ out)
{
  __shared__ u16 yT[64 * 72];   // col-major y2 tile: yT[col*72 + row], 9 KiB

  const int n    = blockIdx.x >> 5;
  const int lt   = blockIdx.x & 31;
  const int tid  = threadIdx.x;
  const int wave = tid >> 6;
  const int lane = tid & 63;
  const int l15  = lane & 15;
  const int g4   = lane >> 4;
  const int colb = lt * 64 + wave * 32;

  const u16* mq = mP + (((size_t)n * 64 * LL + colb + l15) * 4 + g4) * 8;
  const u16* ap = y1 + (size_t)n * CH * LL + (size_t)l15 * LL + g4 * 8;

  f32x4 acc[4][2];
#pragma unroll
  for (int f = 0; f < 4; ++f)
#pragma unroll
    for (int h = 0; h < 2; ++h)
#pragma unroll
      for (int r = 0; r < 4; ++r) acc[f][h][r] = 0.f;

  s16x8 bA0, bA1, bB0, bB1, aA[4], aB[4];

#define K2_LOAD(B0, B1, AV, KB)                                              \
  {                                                                          \
    const u16* _mq = mq + (size_t)(KB) * 65536;                              \
    B0 = *(const s16x8*)(_mq);                                               \
    B1 = *(const s16x8*)(_mq + 512);                                         \
    const u16* _ap = ap + (KB) * 32;                                         \
    _Pragma("unroll") for (int f = 0; f < 4; ++f)                            \
      AV[f] = *(const s16x8*)(_ap + (size_t)(f * 16) * LL);                  \
  }

#define K2_COMP(B0, B1, AV)                                                  \
  _Pragma("unroll") for (int f = 0; f < 4; ++f) {                            \
    acc[f][0] = __builtin_amdgcn_mfma_f32_16x16x32_bf16(AV[f], B0, acc[f][0], 0, 0, 0); \
    acc[f][1] = __builtin_amdgcn_mfma_f32_16x16x32_bf16(AV[f], B1, acc[f][1], 0, 0, 0); \
  }

  K2_LOAD(bA0, bA1, aA, 63)
#pragma unroll 1
  for (int kb = 63; kb >= 1; kb -= 2) {
    K2_LOAD(bB0, bB1, aB, kb - 1)
    K2_COMP(bA0, bA1, aA)
    if (kb - 2 >= 0) K2_LOAD(bA0, bA1, aA, kb - 2)
    K2_COMP(bB0, bB1, aB)
  }

  // ---- epilogue: y2 (acc) -> LDS col-major bf16 ----
#pragma unroll
  for (int f = 0; f < 4; ++f)
#pragma unroll
    for (int h = 0; h < 2; ++h) {
      const int c = wave * 32 + l15 + 16 * h;
      *(s16x4*)(&yT[c * 72 + f * 16 + g4 * 4]) = pack4c(acc[f][h]);
    }
  __syncthreads();

  // ---- projection: out = Wb(128x192) * [xb;y1;y2] + b ----
  f32x4 acc2[8][2];
#pragma unroll
  for (int f = 0; f < 8; ++f)
#pragma unroll
    for (int h = 0; h < 2; ++h)
#pragma unroll
      for (int r = 0; r < 4; ++r) acc2[f][h][r] = 0.f;

  const size_t cb = (size_t)n * CH * LL + colb + l15;
  const u16* xp  = xb + cb + (size_t)(g4 * 8) * LL;
  const u16* y1p = y1 + cb + (size_t)(g4 * 8) * LL;
  const u16* wq  = Wb + (size_t)l15 * 192 + g4 * 8;

#pragma unroll
  for (int kc = 0; kc < 6; ++kc) {
    const int k0 = kc * 32;
    s16x8 b0, b1;
    if (kc < 4) {
      const u16* src = (kc < 2) ? (xp + (size_t)k0 * LL)
                                : (y1p + (size_t)(k0 - 64) * LL);
#pragma unroll
      for (int j = 0; j < 8; ++j) {
        b0[j] = (short)src[(size_t)j * LL];
        b1[j] = (short)src[(size_t)j * LL + 16];
      }
    } else {
      const int rb = (kc - 4) * 32 + g4 * 8;
      b0 = *(const s16x8*)(&yT[(wave * 32 + l15) * 72 + rb]);
      b1 = *(const s16x8*)(&yT[(wave * 32 + l15 + 16) * 72 + rb]);
    }
#pragma unroll
    for (int f = 0; f < 8; ++f) {
      s16x8 af = *(const s16x8*)(wq + (size_t)(f * 16) * 192 + k0);
      acc2[f][0] = __builtin_amdgcn_mfma_f32_16x16x32_bf16(af, b0, acc2[f][0], 0, 0, 0);
      acc2[f][1] = __builtin_amdgcn_mfma_f32_16x16x32_bf16(af, b1, acc2[f][1], 0, 0, 0);
    }
  }

  float* op = out + (size_t)n * OUTC * LL + colb + l15;
#pragma unroll
  for (int f = 0; f < 8; ++f)
#pragma unroll
    for (int r = 0; r < 4; ++r) {
      const int row = f * 16 + g4 * 4 + r;
      op[(size_t)row * LL]      = acc2[f][0][r] + bias[row];
      op[(size_t)row * LL + 16] = acc2[f][1][r] + bias[row];
    }
}

extern "C" void kernel_launch(void* const* d_in, const int* in_sizes, int n_in,
                              void* d_out, int out_size, void* d_ws, size_t ws_size,
                              hipStream_t stream)
{
  const float* x = (const float*)d_in[0];
  const float* m = (const float*)d_in[1];
  const float* W = (const float*)d_in[2];
  const float* b = (const float*)d_in[3];
  float* out = (float*)d_out;

  // workspace layout (u16 elems): y1 | xb | Wb | mP
  u16* y1 = (u16*)d_ws;                          //  8 MiB
  u16* xb = y1 + (size_t)NB * CH * LL;           //  8 MiB
  u16* Wb = xb + (size_t)NB * CH * LL;           // 48 KiB
  u16* mP = (u16*)((char*)d_ws + (25u << 20));   // 256 MiB, 1 MiB-aligned

  cvt_inputs<<<dim3(2060), dim3(256), 0, stream>>>(x, W, xb, Wb);
  prop1_pack<<<dim3(NB * 32), dim3(128), 0, stream>>>(xb, m, y1, mP);
  prop2_proj<<<dim3(NB * 32), dim3(128), 0, stream>>>(y1, mP, xb, Wb, b, out);
}

// Round 11
// 270.405 us; speedup vs baseline: 1.1065x; 1.1065x over previous
//
#include <hip/hip_runtime.h>
#include <hip/hip_bf16.h>

#define NB   32
#define CH   64
#define LL   2048
#define OUTC 128

typedef float  f32x4  __attribute__((ext_vector_type(4)));
typedef short  s16x8  __attribute__((ext_vector_type(8)));
typedef short  s16x4  __attribute__((ext_vector_type(4)));
typedef unsigned short u16;

__device__ __forceinline__ u16 f2bf(float f) {
  unsigned int u = __builtin_bit_cast(unsigned int, f);
  u += 0x7FFFu + ((u >> 16) & 1u);           // RNE (scalar epilogue use)
  return (u16)(u >> 16);
}

// 8x fp32 -> 8x bf16 via v_cvt_pk_bf16_f32 (compiler-emitted, RNE)
__device__ __forceinline__ s16x8 pack8c(const float* v) {
  s16x8 r;
#pragma unroll
  for (int j = 0; j < 8; j += 2) {
    __hip_bfloat162 h = __float22bfloat162_rn(make_float2(v[j], v[j + 1]));
    short2 s;
    __builtin_memcpy(&s, &h, sizeof(s));
    r[j] = s.x; r[j + 1] = s.y;
  }
  return r;
}

__device__ __forceinline__ s16x4 pack4c(const f32x4& v) {
  s16x4 r;
  __hip_bfloat162 h0 = __float22bfloat162_rn(make_float2(v[0], v[1]));
  __hip_bfloat162 h1 = __float22bfloat162_rn(make_float2(v[2], v[3]));
  short2 s0, s1;
  __builtin_memcpy(&s0, &h0, sizeof(s0));
  __builtin_memcpy(&s1, &h1, sizeof(s1));
  r[0] = s0.x; r[1] = s0.y; r[2] = s1.x; r[3] = s1.y;
  return r;
}

// ---------------------------------------------------------------------------
// K0: x (fp32->bf16), W (fp32->bf16)
// ---------------------------------------------------------------------------
#define NX (NB * CH * LL)          // 4,194,304
#define NW (OUTC * 3 * CH)         // 24,576
__global__ __launch_bounds__(256)
void cvt_inputs(const float* __restrict__ x, const float* __restrict__ W,
                u16* __restrict__ xb, u16* __restrict__ Wb)
{
  const size_t t8 = ((size_t)blockIdx.x * 256 + threadIdx.x) * 8;
  if (t8 < NX) {
    float v[8];
    *(f32x4*)(v)     = *(const f32x4*)(x + t8);
    *(f32x4*)(v + 4) = *(const f32x4*)(x + t8 + 4);
    *(s16x8*)(xb + t8) = pack8c(v);
  } else if (t8 - NX < NW) {
    const size_t w8 = t8 - NX;
    float v[8];
    *(f32x4*)(v)     = *(const f32x4*)(W + w8);
    *(f32x4*)(v + 4) = *(const f32x4*)(W + w8 + 4);
    *(s16x8*)(Wb + w8) = pack8c(v);
  }
}

// ---------------------------------------------------------------------------
// K1: y1[n] = xb[n] * m[n]  (+ writes mP bf16 B-fragments for K2)
// Quad-buffered gload_lds pipeline, prefetch distance 3; A-fragments
// register-prefetched distance 1 and issued BEFORE the GLOADs so the
// compiler's MFMA wait never drains the m-tile stream.
// Per-iter issue: [A:4][G:4][St:2]; steady barrier wait = vmcnt(22).
// (256-thread / 128-col geometry — the 271.5 µs configuration.)
// ---------------------------------------------------------------------------
__global__ __launch_bounds__(256, 2)
void prop1_pack(const u16* __restrict__ xb, const float* __restrict__ m,
                u16* __restrict__ y1, u16* __restrict__ mP)
{
  __shared__ float smem[4][32 * 128];   // 64 KiB quad-buffered 32x128 fp32 tile

  const int n    = blockIdx.x >> 4;
  const int lt   = blockIdx.x & 15;
  const int tid  = threadIdx.x;
  const int wave = tid >> 6;
  const int lane = tid & 63;
  const int l15  = lane & 15;
  const int g4   = lane >> 4;
  const int colb = lt * 128 + wave * 32;

  const float* mn   = m + (size_t)n * LL * LL + lt * 128;
  const float* gsrc = mn + (size_t)(wave * 8 + (lane >> 5)) * LL + (lane & 31) * 4;
  const u16*   ap   = xb + (size_t)n * CH * LL + (size_t)l15 * LL + g4 * 8;
  u16* q0 = mP + (((size_t)n * 64 * LL + colb + l15) * 4 + g4) * 8; // + kb*65536, h*512
  u16* o  = y1 + (size_t)n * CH * LL + colb + l15;

  f32x4 acc[4][2];
#pragma unroll
  for (int f = 0; f < 4; ++f)
#pragma unroll
    for (int h = 0; h < 2; ++h)
#pragma unroll
      for (int r = 0; r < 4; ++r) acc[f][h][r] = 0.f;

  s16x8 aP[4], aQ[4];

#define ALOAD(R, KB)                                                          \
  { const u16* _ap = ap + (KB) * 32;                                          \
    _Pragma("unroll") for (int f = 0; f < 4; ++f)                             \
      R[f] = *(const s16x8*)(_ap + (size_t)(f * 16) * LL); }

#define GLOAD(BI, KB)                                                         \
  { float* _sb = smem[BI];                                                    \
    _Pragma("unroll") for (int i = 0; i < 4; ++i) {                           \
      const float* _g = gsrc + (size_t)((KB) * 32 + i * 2) * LL;              \
      __builtin_amdgcn_global_load_lds(                                       \
        (const __attribute__((address_space(1))) void*)_g,                    \
        (__attribute__((address_space(3))) void*)(_sb + (wave * 4 + i) * 256),\
        16, 0, 0); } }

  // prologue: A(0) FIRST (oldest), then tiles 0,1,2
  ALOAD(aP, 0)
  __builtin_amdgcn_sched_barrier(0);
  GLOAD(0, 0) GLOAD(1, 1) GLOAD(2, 2)
  __builtin_amdgcn_sched_barrier(0);
  asm volatile("s_waitcnt vmcnt(8)" ::: "memory");   // tile 0 landed (G1+G2 = 8 newer)
  __builtin_amdgcn_s_barrier();
  __builtin_amdgcn_sched_barrier(0);

  // one K-step. Issue order: A(kb+1) | G(kb+3) | ds_read/pack/store/MFMA | wait+barrier
#define K1_STEP(KB, CUR, NXT, VN, LAST)                                       \
  {                                                                           \
    if (!(LAST)) {                                                            \
      ALOAD(NXT, ((KB) + 1 < 64 ? (KB) + 1 : 63))                             \
      __builtin_amdgcn_sched_barrier(0);                                      \
      GLOAD(((KB) + 3) & 3, ((KB) + 3 < 64 ? (KB) + 3 : 63))                  \
      __builtin_amdgcn_sched_barrier(0);                                      \
    }                                                                         \
    const float* _t = smem[(KB) & 3] + wave * 32 + l15;                       \
    float _bv0[8], _bv1[8];                                                   \
    _Pragma("unroll") for (int j = 0; j < 8; ++j) {                           \
      _bv0[j] = _t[(g4 * 8 + j) * 128];                                       \
      _bv1[j] = _t[(g4 * 8 + j) * 128 + 16];                                  \
    }                                                                         \
    s16x8 _b0 = pack8c(_bv0), _b1 = pack8c(_bv1);                             \
    u16* _q = q0 + (size_t)(KB) * 65536;                                      \
    *(s16x8*)(_q)       = _b0;                                                \
    *(s16x8*)(_q + 512) = _b1;                                                \
    _Pragma("unroll") for (int f = 0; f < 4; ++f) {                           \
      acc[f][0] = __builtin_amdgcn_mfma_f32_16x16x32_bf16(CUR[f], _b0, acc[f][0], 0, 0, 0); \
      acc[f][1] = __builtin_amdgcn_mfma_f32_16x16x32_bf16(CUR[f], _b1, acc[f][1], 0, 0, 0); \
    }                                                                         \
    if (!(LAST)) {                                                            \
      __builtin_amdgcn_sched_barrier(0);                                      \
      asm volatile("s_waitcnt vmcnt(" VN ")" ::: "memory");                   \
      __builtin_amdgcn_s_barrier();                                           \
      __builtin_amdgcn_sched_barrier(0);                                      \
    }                                                                         \
  }

  K1_STEP(0, aP, aQ, "14", false)   // retire G(1): G2+A1+G3+St0 = 14 newer
  K1_STEP(1, aQ, aP, "20", false)   // retire G(2): 20 newer
#pragma unroll 1
  for (int kb = 2; kb < 62; kb += 2) {
    K1_STEP(kb,     aP, aQ, "22", false)
    K1_STEP(kb + 1, aQ, aP, "22", false)
  }
  K1_STEP(62, aP, aQ, "22", false)
  K1_STEP(63, aQ, aP, "0",  true)

#pragma unroll
  for (int f = 0; f < 4; ++f)
#pragma unroll
    for (int r = 0; r < 4; ++r) {
      const int row = f * 16 + g4 * 4 + r;
      o[(size_t)row * LL]      = f2bf(acc[f][0][r]);
      o[(size_t)row * LL + 16] = f2bf(acc[f][1][r]);
    }
}

// ---------------------------------------------------------------------------
// K2: y2 = y1 * m (from mP) FUSED with projection epilogue.
// SINGLE CHANGE vs the 271.5 µs kernel: kb loop runs 63 -> 0 so the
// L3-resident TAIL of mP (written last by K1) is consumed first.
// ---------------------------------------------------------------------------
__global__ __launch_bounds__(256, 2)
void prop2_proj(const u16* __restrict__ y1, const u16* __restrict__ mP,
                const u16* __restrict__ xb, const u16* __restrict__ Wb,
                const float* __restrict__ bias, float* __restrict__ out)
{
  __shared__ u16 yT[128 * 72];   // col-major y2 tile: yT[col*72 + row], 18 KiB

  const int n    = blockIdx.x >> 4;
  const int lt   = blockIdx.x & 15;
  const int tid  = threadIdx.x;
  const int wave = tid >> 6;
  const int lane = tid & 63;
  const int l15  = lane & 15;
  const int g4   = lane >> 4;
  const int colb = lt * 128 + wave * 32;

  const u16* mq = mP + (((size_t)n * 64 * LL + colb + l15) * 4 + g4) * 8;
  const u16* ap = y1 + (size_t)n * CH * LL + (size_t)l15 * LL + g4 * 8;

  f32x4 acc[4][2];
#pragma unroll
  for (int f = 0; f < 4; ++f)
#pragma unroll
    for (int h = 0; h < 2; ++h)
#pragma unroll
      for (int r = 0; r < 4; ++r) acc[f][h][r] = 0.f;

  s16x8 bA0, bA1, bB0, bB1, aA[4], aB[4];

#define K2_LOAD(B0, B1, AV, KB)                                              \
  {                                                                          \
    const u16* _mq = mq + (size_t)(KB) * 65536;                              \
    B0 = *(const s16x8*)(_mq);                                               \
    B1 = *(const s16x8*)(_mq + 512);                                         \
    const u16* _ap = ap + (KB) * 32;                                         \
    _Pragma("unroll") for (int f = 0; f < 4; ++f)                            \
      AV[f] = *(const s16x8*)(_ap + (size_t)(f * 16) * LL);                  \
  }

#define K2_COMP(B0, B1, AV)                                                  \
  _Pragma("unroll") for (int f = 0; f < 4; ++f) {                            \
    acc[f][0] = __builtin_amdgcn_mfma_f32_16x16x32_bf16(AV[f], B0, acc[f][0], 0, 0, 0); \
    acc[f][1] = __builtin_amdgcn_mfma_f32_16x16x32_bf16(AV[f], B1, acc[f][1], 0, 0, 0); \
  }

  K2_LOAD(bA0, bA1, aA, 63)
#pragma unroll 1
  for (int kb = 63; kb >= 1; kb -= 2) {
    K2_LOAD(bB0, bB1, aB, kb - 1)
    K2_COMP(bA0, bA1, aA)
    if (kb - 2 >= 0) K2_LOAD(bA0, bA1, aA, kb - 2)
    K2_COMP(bB0, bB1, aB)
  }

  // ---- epilogue: y2 (acc) -> LDS col-major bf16 ----
#pragma unroll
  for (int f = 0; f < 4; ++f)
#pragma unroll
    for (int h = 0; h < 2; ++h) {
      const int c = wave * 32 + l15 + 16 * h;
      *(s16x4*)(&yT[c * 72 + f * 16 + g4 * 4]) = pack4c(acc[f][h]);
    }
  __syncthreads();

  // ---- projection: out = Wb(128x192) * [xb;y1;y2] + b ----
  f32x4 acc2[8][2];
#pragma unroll
  for (int f = 0; f < 8; ++f)
#pragma unroll
    for (int h = 0; h < 2; ++h)
#pragma unroll
      for (int r = 0; r < 4; ++r) acc2[f][h][r] = 0.f;

  const size_t cb = (size_t)n * CH * LL + colb + l15;
  const u16* xp  = xb + cb + (size_t)(g4 * 8) * LL;
  const u16* y1p = y1 + cb + (size_t)(g4 * 8) * LL;
  const u16* wq  = Wb + (size_t)l15 * 192 + g4 * 8;

#pragma unroll
  for (int kc = 0; kc < 6; ++kc) {
    const int k0 = kc * 32;
    s16x8 b0, b1;
    if (kc < 4) {
      const u16* src = (kc < 2) ? (xp + (size_t)k0 * LL)
                                : (y1p + (size_t)(k0 - 64) * LL);
#pragma unroll
      for (int j = 0; j < 8; ++j) {
        b0[j] = (short)src[(size_t)j * LL];
        b1[j] = (short)src[(size_t)j * LL + 16];
      }
    } else {
      const int rb = (kc - 4) * 32 + g4 * 8;
      b0 = *(const s16x8*)(&yT[(wave * 32 + l15) * 72 + rb]);
      b1 = *(const s16x8*)(&yT[(wave * 32 + l15 + 16) * 72 + rb]);
    }
#pragma unroll
    for (int f = 0; f < 8; ++f) {
      s16x8 af = *(const s16x8*)(wq + (size_t)(f * 16) * 192 + k0);
      acc2[f][0] = __builtin_amdgcn_mfma_f32_16x16x32_bf16(af, b0, acc2[f][0], 0, 0, 0);
      acc2[f][1] = __builtin_amdgcn_mfma_f32_16x16x32_bf16(af, b1, acc2[f][1], 0, 0, 0);
    }
  }

  float* op = out + (size_t)n * OUTC * LL + colb + l15;
#pragma unroll
  for (int f = 0; f < 8; ++f)
#pragma unroll
    for (int r = 0; r < 4; ++r) {
      const int row = f * 16 + g4 * 4 + r;
      op[(size_t)row * LL]      = acc2[f][0][r] + bias[row];
      op[(size_t)row * LL + 16] = acc2[f][1][r] + bias[row];
    }
}

extern "C" void kernel_launch(void* const* d_in, const int* in_sizes, int n_in,
                              void* d_out, int out_size, void* d_ws, size_t ws_size,
                              hipStream_t stream)
{
  const float* x = (const float*)d_in[0];
  const float* m = (const float*)d_in[1];
  const float* W = (const float*)d_in[2];
  const float* b = (const float*)d_in[3];
  float* out = (float*)d_out;

  // workspace layout (u16 elems): y1 | xb | Wb | mP
  u16* y1 = (u16*)d_ws;                          //  8 MiB
  u16* xb = y1 + (size_t)NB * CH * LL;           //  8 MiB
  u16* Wb = xb + (size_t)NB * CH * LL;           // 48 KiB
  u16* mP = (u16*)((char*)d_ws + (25u << 20));   // 256 MiB, 1 MiB-aligned

  cvt_inputs<<<dim3(2060), dim3(256), 0, stream>>>(x, W, xb, Wb);
  prop1_pack<<<dim3(NB * 16), dim3(256), 0, stream>>>(xb, m, y1, mP);
  prop2_proj<<<dim3(NB * 16), dim3(256), 0, stream>>>(y1, mP, xb, Wb, b, out);
}